// Round 11
// baseline (536.045 us; speedup 1.0000x reference)
//
#include <hip/hip_runtime.h>
#include <hip/hip_bf16.h>

#define N_TOK 32768
#define DIM   256
#define KCB   8192
#define CAP   64
#define MARGIN 1.75e-4f

typedef __attribute__((ext_vector_type(8))) short short8v;   // 8 bf16
typedef __attribute__((ext_vector_type(4))) float f32x4;

__device__ __forceinline__ unsigned int mono_f32(float f) {
    unsigned int u = __float_as_uint(f);
    return (u >> 31) ? ~u : (u | 0x80000000u);
}
__device__ __forceinline__ float invmono_f32(unsigned int m) {
    unsigned int u = (m & 0x80000000u) ? (m & 0x7FFFFFFFu) : ~m;
    return __uint_as_float(u);
}
__device__ __forceinline__ unsigned long long shfl_xor_u64(unsigned long long v, int m) {
    unsigned int lo = (unsigned int)v, hi = (unsigned int)(v >> 32);
    lo = __shfl_xor(lo, m, 64);
    hi = __shfl_xor(hi, m, 64);
    return ((unsigned long long)hi << 32) | lo;
}
__device__ __forceinline__ void gl_lds16(const void* g, void* l) {
    __builtin_amdgcn_global_load_lds(
        (const __attribute__((address_space(1))) unsigned int*)g,
        (__attribute__((address_space(3))) unsigned int*)l, 16, 0, 0);
}
__device__ __forceinline__ unsigned int rne16(float f) {
    unsigned int b = __float_as_uint(f);
    return (b + 0x7FFFu + ((b >> 16) & 1u)) >> 16;
}

// ---------------------------------------------------------------------------
// transpose w_out [D][D] -> wT[j][d]
// ---------------------------------------------------------------------------
__global__ __launch_bounds__(256) void transpose_w(const float* __restrict__ w,
                                                   float* __restrict__ wT) {
    __shared__ float tile[32][33];
    int bx = blockIdx.x & 7, by = blockIdx.x >> 3;
    int x0 = bx * 32, y0 = by * 32;
    int tx = threadIdx.x & 31, ty = threadIdx.x >> 5;
    #pragma unroll
    for (int i = 0; i < 32; i += 8)
        tile[ty + i][tx] = w[(y0 + ty + i) * DIM + x0 + tx];
    __syncthreads();
    #pragma unroll
    for (int i = 0; i < 32; i += 8)
        wT[(x0 + ty + i) * DIM + y0 + tx] = tile[tx][ty + i];
}

// ---------------------------------------------------------------------------
// codebook[k][d] = sum_j emb[k][j]*w_out[d][j], sequential-j FMA chain (BLAS order)
// ---------------------------------------------------------------------------
#define KPB 8
__global__ __launch_bounds__(256) void build_codebook(const float* __restrict__ emb,
                                                      const float* __restrict__ wT,
                                                      float* __restrict__ cb) {
    __shared__ float e[KPB][DIM];
    const int k0 = blockIdx.x * KPB;
    const int t = threadIdx.x;
    for (int i = t; i < KPB * DIM / 4; i += 256)
        ((float4*)&e[0][0])[i] = ((const float4*)(emb + (size_t)k0 * DIM))[i];
    __syncthreads();
    const int d = t;
    float acc[KPB];
    #pragma unroll
    for (int kk = 0; kk < KPB; ++kk) acc[kk] = 0.f;
    for (int j = 0; j < DIM; ++j) {
        float w = wT[j * DIM + d];
        #pragma unroll
        for (int kk = 0; kk < KPB; ++kk)
            acc[kk] = fmaf(e[kk][j], w, acc[kk]);
    }
    #pragma unroll
    for (int kk = 0; kk < KPB; ++kk)
        cb[(size_t)(k0 + kk) * DIM + d] = acc[kk];
}

// ---------------------------------------------------------------------------
// numpy pairwise sum-of-squares (exact np order), 2 threads per row,
// FUSED with fp32->bf16 (RNE) conversion (bfout != null).
// ---------------------------------------------------------------------------
__global__ __launch_bounds__(256) void sumsq_np_bf(const float* __restrict__ a,
                                                   float* __restrict__ out,
                                                   uint4* __restrict__ bfout) {
    #pragma clang fp contract(off)
    int idx = blockIdx.x * 256 + threadIdx.x;
    int r = idx >> 1, h = idx & 1;
    const float* b = a + (size_t)r * DIM + h * 128;
    uint4* dst = bfout ? bfout + ((size_t)r * 32 + h * 16) : (uint4*)0;
    float r0 = 0.f, r1 = 0.f, r2 = 0.f, r3 = 0.f,
          r4 = 0.f, r5 = 0.f, r6 = 0.f, r7 = 0.f;
    #pragma unroll
    for (int i = 0; i < 128; i += 8) {
        float4 p = *(const float4*)(b + i);
        float4 q = *(const float4*)(b + i + 4);
        if (bfout) {
            uint4 u;
            u.x = rne16(p.x) | (rne16(p.y) << 16);
            u.y = rne16(p.z) | (rne16(p.w) << 16);
            u.z = rne16(q.x) | (rne16(q.y) << 16);
            u.w = rne16(q.z) | (rne16(q.w) << 16);
            dst[i >> 3] = u;
        }
        r0 = r0 + p.x * p.x; r1 = r1 + p.y * p.y;
        r2 = r2 + p.z * p.z; r3 = r3 + p.w * p.w;
        r4 = r4 + q.x * q.x; r5 = r5 + q.y * q.y;
        r6 = r6 + q.z * q.z; r7 = r7 + q.w * q.w;
    }
    float half = ((r0 + r1) + (r2 + r3)) + ((r4 + r5) + (r6 + r7));
    float other = __shfl_xor(half, 1, 64);
    if (h == 0) out[r] = half + other;
}

// ---------------------------------------------------------------------------
// Phase 1: bf16 MFMA score GEMM + per-row running max + candidate collection.
// 256x256 tile, 8 waves (4x2 grid, 64x128/wave, acc[4][8]).
// Counted-vmcnt pipeline (T3+T4): K split into 8 stages of 32 elements
// (64 B/row, 32 KiB/stage), 4 LDS buffers, 2-deep prefetch. Steady state
// waits vmcnt(8) — the newest 2 stages stay in flight ACROSS the barrier;
// vmcnt(0) never appears in the main loop.
// Swizzle for 64-B rows: chunk ^= (row&3)^((row>>2)&3) -> fragment reads
// land on 8 distinct 16B bank slots (2-way aliasing = free floor).
// Epilogue: wave-local max -> LDS merge -> ONE atomicMax/row -> append.
// ---------------------------------------------------------------------------
__global__ __launch_bounds__(512, 2) void score_collect(
    const unsigned short* __restrict__ xbf,
    const unsigned short* __restrict__ cbbf,
    unsigned int* __restrict__ gmax,
    unsigned int* __restrict__ ccnt,
    unsigned short* __restrict__ cand)
{
    __shared__ unsigned char lds[131072];   // 4 bufs x (A 16K @0 + B 16K @16K)
    __shared__ float auxm[2][256];
    const int t = threadIdx.x;
    const int l = t & 63, w = t >> 6;
    const int g = l >> 4, c = l & 15;
    const int wr = w >> 1, wc = w & 1;      // 4x2 wave grid: 64 rows x 128 cols
    const int row0 = blockIdx.x * 256;
    const int col0 = blockIdx.y * 256;

    f32x4 acc[4][8];
    #pragma unroll
    for (int m = 0; m < 4; ++m)
        #pragma unroll
        for (int n = 0; n < 8; ++n) acc[m][n] = (f32x4){0.f, 0.f, 0.f, 0.f};

    const char* xg = (const char*)xbf  + (size_t)row0 * 512;
    const char* cg = (const char*)cbbf + (size_t)col0 * 512;

    // stage s covers k-bytes [s*64, s*64+64) of each row; 4 gl_lds16/thread
#define STAGE(b_, s_)                                                          \
    do {                                                                       \
        const int kb_ = (s_) * 64;                                             \
        unsigned char* la_ = lds + (b_) * 32768;                               \
        _Pragma("unroll")                                                      \
        for (int r_ = 0; r_ < 2; ++r_) {          /* A: 256 rows x 4 chunks */ \
            int i_ = r_ * 512 + t;                                             \
            int row_ = i_ >> 2, pc_ = i_ & 3;                                  \
            int sz_ = (row_ ^ (row_ >> 2)) & 3;                                \
            gl_lds16(xg + (size_t)row_ * 512 + kb_ + ((pc_ ^ sz_) * 16),       \
                     la_ + i_ * 16);                                           \
        }                                                                      \
        _Pragma("unroll")                                                      \
        for (int r_ = 0; r_ < 2; ++r_) {          /* B: 256 cols x 4 chunks */ \
            int i_ = r_ * 512 + t;                                             \
            int row_ = i_ >> 2, pc_ = i_ & 3;                                  \
            int sz_ = (row_ ^ (row_ >> 2)) & 3;                                \
            gl_lds16(cg + (size_t)row_ * 512 + kb_ + ((pc_ ^ sz_) * 16),       \
                     la_ + 16384 + i_ * 16);                                   \
        }                                                                      \
    } while (0)

    // per-thread read offsets (chunk swizzle: row%4==c%4, (row>>2)%4==(c>>2)%4)
    const int swq = (g ^ (c & 3) ^ ((c >> 2) & 3)) * 16;

    STAGE(0, 0); STAGE(1, 1); STAGE(2, 2);           // 12 loads in flight
    asm volatile("s_waitcnt vmcnt(8)" ::: "memory"); // stage 0 landed
    __builtin_amdgcn_s_barrier();
    asm volatile("" ::: "memory");

    #pragma unroll
    for (int s = 0; s < 8; ++s) {
        if (s < 5) STAGE((s + 3) & 3, s + 3);        // 2-deep prefetch
        const unsigned char* la = lds + (s & 3) * 32768;
        const unsigned char* lb = la + 16384;
        short8v af[4], bv[8];
        #pragma unroll
        for (int m = 0; m < 4; ++m)
            af[m] = *(const short8v*)(la + (64 * wr + 16 * m + c) * 64 + swq);
        #pragma unroll
        for (int n = 0; n < 8; ++n)
            bv[n] = *(const short8v*)(lb + (128 * wc + 16 * n + c) * 64 + swq);
        #pragma unroll
        for (int m = 0; m < 4; ++m)
            #pragma unroll
            for (int n = 0; n < 8; ++n)
                acc[m][n] = __builtin_amdgcn_mfma_f32_16x16x32_bf16(
                    af[m], bv[n], acc[m][n], 0, 0, 0);
        if (s < 7) {
            if (s <= 4)      asm volatile("s_waitcnt vmcnt(8)" ::: "memory");
            else if (s == 5) asm volatile("s_waitcnt vmcnt(4)" ::: "memory");
            else             asm volatile("s_waitcnt vmcnt(0)" ::: "memory");
            __builtin_amdgcn_s_barrier();
            asm volatile("" ::: "memory");
        }
    }
#undef STAGE

    // ---- epilogue: C/D layout col = c, row = 4*g + j within each 16x16 ----
    // 1) wave-local 128-col max per row -> auxm[wc][row]
    #pragma unroll
    for (int m = 0; m < 4; ++m)
        #pragma unroll
        for (int j = 0; j < 4; ++j) {
            float v = acc[m][0][j];
            #pragma unroll
            for (int n = 1; n < 8; ++n) v = fmaxf(v, acc[m][n][j]);
            #pragma unroll
            for (int msk = 1; msk < 16; msk <<= 1)
                v = fmaxf(v, __shfl_xor(v, msk, 64));
            if (c == 0) auxm[wc][64 * wr + 16 * m + 4 * g + j] = v;
        }
    __syncthreads();

    // 2) wc==0 waves, c==0 lanes: merge halves, ONE atomicMax per row
    if (wc == 0 && c == 0) {
        float vm[16];
        unsigned int ou[16];
        #pragma unroll
        for (int i = 0; i < 16; ++i) {
            int row = 64 * wr + 16 * (i >> 2) + 4 * g + (i & 3);
            vm[i] = fmaxf(auxm[0][row], auxm[1][row]);
        }
        #pragma unroll
        for (int i = 0; i < 16; ++i) {
            int row = 64 * wr + 16 * (i >> 2) + 4 * g + (i & 3);
            ou[i] = atomicMax(&gmax[row0 + row], mono_f32(vm[i]));
        }
        #pragma unroll
        for (int i = 0; i < 16; ++i) {
            int row = 64 * wr + 16 * (i >> 2) + 4 * g + (i & 3);
            auxm[0][row] = fmaxf(vm[i], invmono_f32(ou[i]));
        }
    }
    __syncthreads();

    // 3) all waves: threshold = running global max - margin; append candidates
    #pragma unroll
    for (int m = 0; m < 4; ++m)
        #pragma unroll
        for (int j = 0; j < 4; ++j) {
            int lrow = 64 * wr + 16 * m + 4 * g + j;
            float thr = auxm[0][lrow] - MARGIN;
            #pragma unroll
            for (int n = 0; n < 8; ++n) {
                float s = acc[m][n][j];
                if (s >= thr) {
                    int row = row0 + lrow;
                    unsigned int idx = atomicAdd(&ccnt[row], 1u);
                    if (idx < CAP)
                        cand[((size_t)row << 6) + idx] =
                            (unsigned short)(col0 + 128 * wc + 16 * n + c);
                }
            }
        }
}

// ---------------------------------------------------------------------------
// Exact np-chain distance: ascending-k fp32 fmaf chain (BLAS order).
// ---------------------------------------------------------------------------
__device__ __forceinline__ unsigned long long np_dist_pack(
    const float4* __restrict__ xr4, const float* __restrict__ cb,
    int k, float X2, const float* __restrict__ c2)
{
    #pragma clang fp contract(off)
    const float4* cr4 = (const float4*)(cb + (size_t)k * DIM);
    float a = 0.f;
    #pragma unroll 8
    for (int t4 = 0; t4 < DIM / 4; ++t4) {
        float4 xv = xr4[t4];
        float4 cv = cr4[t4];
        a = fmaf(xv.x, cv.x, a);
        a = fmaf(xv.y, cv.y, a);
        a = fmaf(xv.z, cv.z, a);
        a = fmaf(xv.w, cv.w, a);
    }
    float u  = X2 - 2.0f * a;
    float dd = u + c2[k];
    return ((unsigned long long)mono_f32(dd) << 32) | (unsigned int)k;
}

// ---------------------------------------------------------------------------
// Phase 2: exact rescore of candidates. One wave per row, lane = candidate.
// ---------------------------------------------------------------------------
__global__ __launch_bounds__(256) void exact_select(
    const float* __restrict__ x, const float* __restrict__ cb,
    const float* __restrict__ x2, const float* __restrict__ c2,
    const unsigned int* __restrict__ ccnt, const unsigned short* __restrict__ cand,
    unsigned long long* __restrict__ best)
{
    const int l = threadIdx.x & 63;
    const int row = (blockIdx.x * 256 + threadIdx.x) >> 6;
    const unsigned int cnt = ccnt[row];
    const float4* xr4 = (const float4*)(x + (size_t)row * DIM);
    const float X2 = x2[row];
    unsigned long long bp = ~0ull;

    if (cnt <= CAP) {
        if (l < (int)cnt) {
            int k = (int)cand[((size_t)row << 6) + l];
            bp = np_dist_pack(xr4, cb, k, X2, c2);
        }
    } else {
        for (int k = l; k < KCB; k += 64) {
            unsigned long long pk = np_dist_pack(xr4, cb, k, X2, c2);
            if (pk < bp) bp = pk;
        }
    }
    #pragma unroll
    for (int m = 1; m < 64; m <<= 1) {
        unsigned long long v = shfl_xor_u64(bp, m);
        if (v < bp) bp = v;
    }
    if (l == 0) best[row] = bp;
}

// ---------------------------------------------------------------------------
// fp32 fallback score kernel (used only if ws is too small)
// ---------------------------------------------------------------------------
__global__ __launch_bounds__(256, 4) void score_argmin(const float* __restrict__ x,
                                                       const float* __restrict__ cb,
                                                       const float* __restrict__ c2,
                                                       const float* __restrict__ x2,
                                                       unsigned long long* __restrict__ best) {
    #pragma clang fp contract(off)
    __shared__ float As[16][128];
    __shared__ float Bs[16][128];
    const int row0 = blockIdx.x * 128;
    const int col0 = blockIdx.y * 128;
    const int t = threadIdx.x;
    const int tn = t & 15, tm = t >> 4;
    const int lrow = t >> 1, lseg = (t & 1) * 4;
    float acc[8][8];
    #pragma unroll
    for (int i = 0; i < 8; ++i)
        #pragma unroll
        for (int j = 0; j < 8; ++j) acc[i][j] = 0.f;
    const float* xp = x  + (size_t)(row0 + lrow) * DIM + lseg;
    const float* cp = cb + (size_t)(col0 + lrow) * DIM + lseg;
    for (int k0 = 0; k0 < DIM; k0 += 16) {
        float4 a0 = *(const float4*)(xp + k0);
        float4 a1 = *(const float4*)(xp + k0 + 8);
        float4 b0 = *(const float4*)(cp + k0);
        float4 b1 = *(const float4*)(cp + k0 + 8);
        __syncthreads();
        As[lseg + 0][lrow] = a0.x; As[lseg + 1][lrow] = a0.y;
        As[lseg + 2][lrow] = a0.z; As[lseg + 3][lrow] = a0.w;
        As[8 + lseg + 0][lrow] = a1.x; As[8 + lseg + 1][lrow] = a1.y;
        As[8 + lseg + 2][lrow] = a1.z; As[8 + lseg + 3][lrow] = a1.w;
        Bs[lseg + 0][lrow] = b0.x; Bs[lseg + 1][lrow] = b0.y;
        Bs[lseg + 2][lrow] = b0.z; Bs[lseg + 3][lrow] = b0.w;
        Bs[8 + lseg + 0][lrow] = b1.x; Bs[8 + lseg + 1][lrow] = b1.y;
        Bs[8 + lseg + 2][lrow] = b1.z; Bs[8 + lseg + 3][lrow] = b1.w;
        __syncthreads();
        #pragma unroll
        for (int kk = 0; kk < 16; ++kk) {
            float a[8], b[8];
            *(float4*)(a)     = *(const float4*)&As[kk][tm * 4];
            *(float4*)(a + 4) = *(const float4*)&As[kk][64 + tm * 4];
            *(float4*)(b)     = *(const float4*)&Bs[kk][tn * 4];
            *(float4*)(b + 4) = *(const float4*)&Bs[kk][64 + tn * 4];
            #pragma unroll
            for (int i = 0; i < 8; ++i)
                #pragma unroll
                for (int j = 0; j < 8; ++j)
                    acc[i][j] = fmaf(a[i], b[j], acc[i][j]);
        }
    }
    float c2v[8], x2v[8];
    #pragma unroll
    for (int j = 0; j < 4; ++j) {
        c2v[j]     = c2[col0 + tn * 4 + j];
        c2v[4 + j] = c2[col0 + 64 + tn * 4 + j];
    }
    #pragma unroll
    for (int i = 0; i < 4; ++i) {
        x2v[i]     = x2[row0 + tm * 4 + i];
        x2v[4 + i] = x2[row0 + 64 + tm * 4 + i];
    }
    #pragma unroll
    for (int i = 0; i < 8; ++i) {
        unsigned long long bp = ~0ull;
        #pragma unroll
        for (int j = 0; j < 8; ++j) {
            float tt = 2.0f * acc[i][j];
            float u  = x2v[i] - tt;
            float dd = u + c2v[j];
            int id = col0 + ((j < 4) ? (tn * 4 + j) : (64 + tn * 4 + (j - 4)));
            unsigned long long pk = ((unsigned long long)mono_f32(dd) << 32) | (unsigned int)id;
            if (pk < bp) bp = pk;
        }
        #pragma unroll
        for (int m = 1; m < 16; m <<= 1) {
            unsigned long long v = shfl_xor_u64(bp, m);
            if (v < bp) bp = v;
        }
        if (tn == 0) {
            int gr = row0 + ((i < 4) ? (tm * 4 + i) : (64 + tm * 4 + (i - 4)));
            atomicMin(&best[gr], bp);
        }
    }
}

// ---------------------------------------------------------------------------
// finalize: gather q = cb[id], write quantized + ids(float) + per-row loss
// ---------------------------------------------------------------------------
__global__ __launch_bounds__(256) void finalize(const float* __restrict__ x,
                                                const float* __restrict__ cb,
                                                const unsigned long long* __restrict__ best,
                                                float* __restrict__ out,
                                                float* __restrict__ partial) {
    const int r = blockIdx.x;
    const int d = threadIdx.x;
    const int id = (int)(best[r] & 0xFFFFFFFFu);
    const float q  = cb[(size_t)id * DIM + d];
    const float xv = x[(size_t)r * DIM + d];
    out[(size_t)r * DIM + d] = q;
    float df = xv - q;
    float v = df * df;
    #pragma unroll
    for (int o = 32; o > 0; o >>= 1) v += __shfl_down(v, o, 64);
    __shared__ float w4[4];
    if ((d & 63) == 0) w4[d >> 6] = v;
    __syncthreads();
    if (d == 0) {
        partial[r] = w4[0] + w4[1] + w4[2] + w4[3];
        out[(size_t)N_TOK * DIM + r] = (float)id;
    }
}

// single block: sum 32768 partials, write loss scalar
__global__ __launch_bounds__(256) void reduce_loss(const float* __restrict__ partial,
                                                   float* __restrict__ out) {
    float s = 0.f;
    for (int i = threadIdx.x; i < N_TOK / 4; i += 256) {
        float4 v = ((const float4*)partial)[i];
        s += (v.x + v.y) + (v.z + v.w);
    }
    #pragma unroll
    for (int o = 32; o > 0; o >>= 1) s += __shfl_down(s, o, 64);
    __shared__ float w4[4];
    if ((threadIdx.x & 63) == 0) w4[threadIdx.x >> 6] = s;
    __syncthreads();
    if (threadIdx.x == 0)
        out[(size_t)N_TOK * DIM + N_TOK] =
            (w4[0] + w4[1] + w4[2] + w4[3]) * (1.25f / ((float)N_TOK * (float)DIM));
}

// ---------------------------------------------------------------------------
extern "C" void kernel_launch(void* const* d_in, const int* in_sizes, int n_in,
                              void* d_out, int out_size, void* d_ws, size_t ws_size,
                              hipStream_t stream) {
    const float* x     = (const float*)d_in[0];
    const float* emb   = (const float*)d_in[1];
    const float* w_out = (const float*)d_in[2];
    float* out = (float*)d_out;

    char* ws = (char*)d_ws;
    unsigned long long* best = (unsigned long long*)ws;              //        0 (256 KiB)
    float* x2 = (float*)(ws + 262400);                               //   262400
    float* wT = (float*)(ws + 393472);                               //   393472 (reused as loss partial)
    float* cb = (float*)(ws + 655616);                               //   655616 (8 MiB)
    float* c2 = (float*)(ws + 9044224);                              //  9044224
    unsigned int*   gmax = (unsigned int*)(ws + 9076992);            //  9076992 (128 KiB)
    unsigned int*   ccnt = (unsigned int*)(ws + 9208064);            //  9208064 (128 KiB)
    unsigned short* cand = (unsigned short*)(ws + 9339136);          //  9339136 (4 MiB)
    unsigned short* xbf  = (unsigned short*)(ws + 13533440);         // 13533440 (16 MiB)
    unsigned short* cbbf = (unsigned short*)(ws + 30310656);         // 30310656 (4 MiB)
    float* partial = wT;                                             // 128 KiB, reuse
    const size_t NEED = 34504960;
    const bool useMfma = (ws_size >= NEED);

    transpose_w   <<<64,  256, 0, stream>>>(w_out, wT);
    build_codebook<<<KCB / KPB, 256, 0, stream>>>(emb, wT, cb);
    // fused sumsq + bf16 cast (bf16 outputs only when the MFMA path is live)
    sumsq_np_bf   <<<N_TOK * 2 / 256, 256, 0, stream>>>(x, x2,
                      useMfma ? (uint4*)xbf : (uint4*)0);
    sumsq_np_bf   <<<KCB * 2 / 256, 256, 0, stream>>>(cb, c2,
                      useMfma ? (uint4*)cbbf : (uint4*)0);

    if (useMfma) {
        hipMemsetAsync(gmax, 0, 262144, stream);   // gmax + ccnt contiguous
        score_collect <<<dim3(N_TOK / 256, KCB / 256), 512, 0, stream>>>(
            xbf, cbbf, gmax, ccnt, cand);
        exact_select  <<<N_TOK / 4, 256, 0, stream>>>(x, cb, x2, c2, ccnt, cand, best);
    } else {
        hipMemsetAsync(best, 0xFF, 262144, stream);
        score_argmin  <<<dim3(N_TOK / 128, KCB / 128), 256, 0, stream>>>(x, cb, c2, x2, best);
    }

    finalize      <<<N_TOK, 256, 0, stream>>>(x, cb, best, out, partial);
    reduce_loss   <<<1, 256, 0, stream>>>(partial, out);
}

// Round 12
// 514.707 us; speedup vs baseline: 1.0415x; 1.0415x over previous
//
#include <hip/hip_runtime.h>
#include <hip/hip_bf16.h>

#define N_TOK 32768
#define DIM   256
#define KCB   8192
#define CAP   64
#define MARGIN 1.75e-4f

typedef __attribute__((ext_vector_type(8))) short short8v;   // 8 bf16
typedef __attribute__((ext_vector_type(4))) float f32x4;

__device__ __forceinline__ unsigned int mono_f32(float f) {
    unsigned int u = __float_as_uint(f);
    return (u >> 31) ? ~u : (u | 0x80000000u);
}
__device__ __forceinline__ float invmono_f32(unsigned int m) {
    unsigned int u = (m & 0x80000000u) ? (m & 0x7FFFFFFFu) : ~m;
    return __uint_as_float(u);
}
__device__ __forceinline__ unsigned long long shfl_xor_u64(unsigned long long v, int m) {
    unsigned int lo = (unsigned int)v, hi = (unsigned int)(v >> 32);
    lo = __shfl_xor(lo, m, 64);
    hi = __shfl_xor(hi, m, 64);
    return ((unsigned long long)hi << 32) | lo;
}
__device__ __forceinline__ void gl_lds16(const void* g, void* l) {
    __builtin_amdgcn_global_load_lds(
        (const __attribute__((address_space(1))) unsigned int*)g,
        (__attribute__((address_space(3))) unsigned int*)l, 16, 0, 0);
}
__device__ __forceinline__ unsigned int rne16(float f) {
    unsigned int b = __float_as_uint(f);
    return (b + 0x7FFFu + ((b >> 16) & 1u)) >> 16;
}

// ---------------------------------------------------------------------------
// transpose w_out [D][D] -> wT[j][d]
// ---------------------------------------------------------------------------
__global__ __launch_bounds__(256) void transpose_w(const float* __restrict__ w,
                                                   float* __restrict__ wT) {
    __shared__ float tile[32][33];
    int bx = blockIdx.x & 7, by = blockIdx.x >> 3;
    int x0 = bx * 32, y0 = by * 32;
    int tx = threadIdx.x & 31, ty = threadIdx.x >> 5;
    #pragma unroll
    for (int i = 0; i < 32; i += 8)
        tile[ty + i][tx] = w[(y0 + ty + i) * DIM + x0 + tx];
    __syncthreads();
    #pragma unroll
    for (int i = 0; i < 32; i += 8)
        wT[(x0 + ty + i) * DIM + y0 + tx] = tile[tx][ty + i];
}

// ---------------------------------------------------------------------------
// codebook[k][d] = sum_j emb[k][j]*w_out[d][j], sequential-j FMA chain (BLAS order)
// ---------------------------------------------------------------------------
#define KPB 8
__global__ __launch_bounds__(256) void build_codebook(const float* __restrict__ emb,
                                                      const float* __restrict__ wT,
                                                      float* __restrict__ cb) {
    __shared__ float e[KPB][DIM];
    const int k0 = blockIdx.x * KPB;
    const int t = threadIdx.x;
    for (int i = t; i < KPB * DIM / 4; i += 256)
        ((float4*)&e[0][0])[i] = ((const float4*)(emb + (size_t)k0 * DIM))[i];
    __syncthreads();
    const int d = t;
    float acc[KPB];
    #pragma unroll
    for (int kk = 0; kk < KPB; ++kk) acc[kk] = 0.f;
    for (int j = 0; j < DIM; ++j) {
        float w = wT[j * DIM + d];
        #pragma unroll
        for (int kk = 0; kk < KPB; ++kk)
            acc[kk] = fmaf(e[kk][j], w, acc[kk]);
    }
    #pragma unroll
    for (int kk = 0; kk < KPB; ++kk)
        cb[(size_t)(k0 + kk) * DIM + d] = acc[kk];
}

// ---------------------------------------------------------------------------
// numpy pairwise sum-of-squares (exact np order), 2 threads per row,
// FUSED with fp32->bf16 (RNE) conversion (bfout != null).
// ---------------------------------------------------------------------------
__global__ __launch_bounds__(256) void sumsq_np_bf(const float* __restrict__ a,
                                                   float* __restrict__ out,
                                                   uint4* __restrict__ bfout) {
    #pragma clang fp contract(off)
    int idx = blockIdx.x * 256 + threadIdx.x;
    int r = idx >> 1, h = idx & 1;
    const float* b = a + (size_t)r * DIM + h * 128;
    uint4* dst = bfout ? bfout + ((size_t)r * 32 + h * 16) : (uint4*)0;
    float r0 = 0.f, r1 = 0.f, r2 = 0.f, r3 = 0.f,
          r4 = 0.f, r5 = 0.f, r6 = 0.f, r7 = 0.f;
    #pragma unroll
    for (int i = 0; i < 128; i += 8) {
        float4 p = *(const float4*)(b + i);
        float4 q = *(const float4*)(b + i + 4);
        if (bfout) {
            uint4 u;
            u.x = rne16(p.x) | (rne16(p.y) << 16);
            u.y = rne16(p.z) | (rne16(p.w) << 16);
            u.z = rne16(q.x) | (rne16(q.y) << 16);
            u.w = rne16(q.z) | (rne16(q.w) << 16);
            dst[i >> 3] = u;
        }
        r0 = r0 + p.x * p.x; r1 = r1 + p.y * p.y;
        r2 = r2 + p.z * p.z; r3 = r3 + p.w * p.w;
        r4 = r4 + q.x * q.x; r5 = r5 + q.y * q.y;
        r6 = r6 + q.z * q.z; r7 = r7 + q.w * q.w;
    }
    float half = ((r0 + r1) + (r2 + r3)) + ((r4 + r5) + (r6 + r7));
    float other = __shfl_xor(half, 1, 64);
    if (h == 0) out[r] = half + other;
}

// ---------------------------------------------------------------------------
// Phase 1: bf16 MFMA score GEMM + per-row running max + candidate collection.
// 256x256 tile, 8 waves (4x2 grid, 64x128/wave, acc[4][8]), BK=64, 2 LDS
// buffers (proven R10 layout, 0 conflicts). Counted schedule: stage s+2 is
// issued AFTER the post-compute barrier (buffer free), waited with vmcnt(8)
// one full compute-step later — newest stage always stays in flight; the only
// vmcnt(0) is the final stage. XCD-bijective block decode (4096 = 8 x 512):
// XCD k owns row-tiles bx ≡ k (mod 8) -> per-XCD L2 working set ~2 MB A-slice
// + hot 128 KB B panel.
// ---------------------------------------------------------------------------
__global__ __launch_bounds__(512, 2) void score_collect(
    const unsigned short* __restrict__ xbf,
    const unsigned short* __restrict__ cbbf,
    unsigned int* __restrict__ gmax,
    unsigned int* __restrict__ ccnt,
    unsigned short* __restrict__ cand)
{
    __shared__ unsigned char lds[131072];   // 2 bufs x (A 32K + B 32K)
    __shared__ float auxm[2][256];
    const int t = threadIdx.x;
    const int l = t & 63, w = t >> 6;
    const int g = l >> 4, c = l & 15;
    const int wr = w >> 1, wc = w & 1;      // 4x2 wave grid: 64 rows x 128 cols
    // XCD-aware decode: bid%8 = XCD; each XCD sweeps 16 row-tiles x 32 col-tiles
    const int bid = blockIdx.x;
    const int bx = (bid & 7) + 8 * ((bid >> 3) & 15);   // row-tile 0..127
    const int by = bid >> 7;                            // col-tile 0..31
    const int row0 = bx * 256;
    const int col0 = by * 256;

    f32x4 acc[4][8];
    #pragma unroll
    for (int m = 0; m < 4; ++m)
        #pragma unroll
        for (int n = 0; n < 8; ++n) acc[m][n] = (f32x4){0.f, 0.f, 0.f, 0.f};

    const char* xg = (const char*)xbf  + (size_t)row0 * 512;
    const char* cg = (const char*)cbbf + (size_t)col0 * 512;

#define STAGE(buf, ks)                                                         \
    do {                                                                       \
        const int kb_ = (ks) * 128;                                            \
        unsigned char* la_ = lds + (buf) * 65536;                              \
        _Pragma("unroll")                                                      \
        for (int r_ = 0; r_ < 4; ++r_) {            /* A: 256 rows x 8 chunks */\
            int i_ = r_ * 512 + t;                                             \
            int row_ = i_ >> 3, pc_ = i_ & 7;                                  \
            gl_lds16(xg + (size_t)row_ * 512 + kb_ + ((pc_ ^ (row_ & 7)) * 16),\
                     la_ + i_ * 16);                                           \
        }                                                                      \
        _Pragma("unroll")                                                      \
        for (int r_ = 0; r_ < 4; ++r_) {            /* B: 256 cols x 8 chunks */\
            int i_ = r_ * 512 + t;                                             \
            int row_ = i_ >> 3, pc_ = i_ & 7;                                  \
            gl_lds16(cg + (size_t)row_ * 512 + kb_ + ((pc_ ^ (row_ & 7)) * 16),\
                     la_ + 32768 + i_ * 16);                                   \
        }                                                                      \
    } while (0)

#define COMPUTE(buf)                                                           \
    do {                                                                       \
        const unsigned char* la_ = lds + (buf) * 65536;                        \
        const unsigned char* lb_ = la_ + 32768;                                \
        _Pragma("unroll")                                                      \
        for (int kk = 0; kk < 2; ++kk) {                                       \
            const int sw_ = ((kk * 4 + g) ^ (c & 7)) * 16;                     \
            short8v af[4], bv[8];                                              \
            _Pragma("unroll")                                                  \
            for (int m = 0; m < 4; ++m)                                        \
                af[m] = *(const short8v*)(la_ + (64 * wr + 16 * m + c) * 128 + sw_); \
            _Pragma("unroll")                                                  \
            for (int n = 0; n < 8; ++n)                                        \
                bv[n] = *(const short8v*)(lb_ + (128 * wc + 16 * n + c) * 128 + sw_); \
            _Pragma("unroll")                                                  \
            for (int m = 0; m < 4; ++m)                                        \
                _Pragma("unroll")                                              \
                for (int n = 0; n < 8; ++n)                                    \
                    acc[m][n] = __builtin_amdgcn_mfma_f32_16x16x32_bf16(       \
                        af[m], bv[n], acc[m][n], 0, 0, 0);                     \
        }                                                                      \
    } while (0)

    // prologue: stages 0,1 in flight; wait stage 0 only
    STAGE(0, 0); STAGE(1, 1);
    asm volatile("s_waitcnt vmcnt(8)" ::: "memory");
    __builtin_amdgcn_s_barrier();
    asm volatile("" ::: "memory");

    // s = 0
    COMPUTE(0);
    __builtin_amdgcn_s_barrier();          // all waves done reading buf0
    asm volatile("" ::: "memory");
    STAGE(0, 2);                           // refill buf0 (stage 2)
    asm volatile("s_waitcnt vmcnt(8)" ::: "memory");   // stage 1 landed
    __builtin_amdgcn_s_barrier();
    asm volatile("" ::: "memory");

    // s = 1
    COMPUTE(1);
    __builtin_amdgcn_s_barrier();          // all waves done reading buf1
    asm volatile("" ::: "memory");
    STAGE(1, 3);                           // refill buf1 (stage 3)
    asm volatile("s_waitcnt vmcnt(8)" ::: "memory");   // stage 2 landed
    __builtin_amdgcn_s_barrier();
    asm volatile("" ::: "memory");

    // s = 2
    COMPUTE(0);
    asm volatile("s_waitcnt vmcnt(0)" ::: "memory");   // stage 3 landed (last)
    __builtin_amdgcn_s_barrier();
    asm volatile("" ::: "memory");

    // s = 3
    COMPUTE(1);
#undef STAGE
#undef COMPUTE

    // ---- epilogue: C/D layout col = c, row = 4*g + j within each 16x16 ----
    // 1) wave-local 128-col max per row -> auxm[wc][row]
    #pragma unroll
    for (int m = 0; m < 4; ++m)
        #pragma unroll
        for (int j = 0; j < 4; ++j) {
            float v = acc[m][0][j];
            #pragma unroll
            for (int n = 1; n < 8; ++n) v = fmaxf(v, acc[m][n][j]);
            #pragma unroll
            for (int msk = 1; msk < 16; msk <<= 1)
                v = fmaxf(v, __shfl_xor(v, msk, 64));
            if (c == 0) auxm[wc][64 * wr + 16 * m + 4 * g + j] = v;
        }
    __syncthreads();

    // 2) wc==0 waves, c==0 lanes: merge halves, ONE atomicMax per row
    if (wc == 0 && c == 0) {
        float vm[16];
        unsigned int ou[16];
        #pragma unroll
        for (int i = 0; i < 16; ++i) {
            int row = 64 * wr + 16 * (i >> 2) + 4 * g + (i & 3);
            vm[i] = fmaxf(auxm[0][row], auxm[1][row]);
        }
        #pragma unroll
        for (int i = 0; i < 16; ++i) {
            int row = 64 * wr + 16 * (i >> 2) + 4 * g + (i & 3);
            ou[i] = atomicMax(&gmax[row0 + row], mono_f32(vm[i]));
        }
        #pragma unroll
        for (int i = 0; i < 16; ++i) {
            int row = 64 * wr + 16 * (i >> 2) + 4 * g + (i & 3);
            auxm[0][row] = fmaxf(vm[i], invmono_f32(ou[i]));
        }
    }
    __syncthreads();

    // 3) all waves: threshold = running global max - margin; append candidates
    #pragma unroll
    for (int m = 0; m < 4; ++m)
        #pragma unroll
        for (int j = 0; j < 4; ++j) {
            int lrow = 64 * wr + 16 * m + 4 * g + j;
            float thr = auxm[0][lrow] - MARGIN;
            #pragma unroll
            for (int n = 0; n < 8; ++n) {
                float s = acc[m][n][j];
                if (s >= thr) {
                    int row = row0 + lrow;
                    unsigned int idx = atomicAdd(&ccnt[row], 1u);
                    if (idx < CAP)
                        cand[((size_t)row << 6) + idx] =
                            (unsigned short)(col0 + 128 * wc + 16 * n + c);
                }
            }
        }
}

// ---------------------------------------------------------------------------
// Exact np-chain distance: ascending-k fp32 fmaf chain (BLAS order).
// ---------------------------------------------------------------------------
__device__ __forceinline__ unsigned long long np_dist_pack(
    const float4* __restrict__ xr4, const float* __restrict__ cb,
    int k, float X2, const float* __restrict__ c2)
{
    #pragma clang fp contract(off)
    const float4* cr4 = (const float4*)(cb + (size_t)k * DIM);
    float a = 0.f;
    #pragma unroll 8
    for (int t4 = 0; t4 < DIM / 4; ++t4) {
        float4 xv = xr4[t4];
        float4 cv = cr4[t4];
        a = fmaf(xv.x, cv.x, a);
        a = fmaf(xv.y, cv.y, a);
        a = fmaf(xv.z, cv.z, a);
        a = fmaf(xv.w, cv.w, a);
    }
    float u  = X2 - 2.0f * a;
    float dd = u + c2[k];
    return ((unsigned long long)mono_f32(dd) << 32) | (unsigned int)k;
}

// ---------------------------------------------------------------------------
// Phase 2: exact rescore of candidates. One wave per row, lane = candidate.
// ---------------------------------------------------------------------------
__global__ __launch_bounds__(256) void exact_select(
    const float* __restrict__ x, const float* __restrict__ cb,
    const float* __restrict__ x2, const float* __restrict__ c2,
    const unsigned int* __restrict__ ccnt, const unsigned short* __restrict__ cand,
    unsigned long long* __restrict__ best)
{
    const int l = threadIdx.x & 63;
    const int row = (blockIdx.x * 256 + threadIdx.x) >> 6;
    const unsigned int cnt = ccnt[row];
    const float4* xr4 = (const float4*)(x + (size_t)row * DIM);
    const float X2 = x2[row];
    unsigned long long bp = ~0ull;

    if (cnt <= CAP) {
        if (l < (int)cnt) {
            int k = (int)cand[((size_t)row << 6) + l];
            bp = np_dist_pack(xr4, cb, k, X2, c2);
        }
    } else {
        for (int k = l; k < KCB; k += 64) {
            unsigned long long pk = np_dist_pack(xr4, cb, k, X2, c2);
            if (pk < bp) bp = pk;
        }
    }
    #pragma unroll
    for (int m = 1; m < 64; m <<= 1) {
        unsigned long long v = shfl_xor_u64(bp, m);
        if (v < bp) bp = v;
    }
    if (l == 0) best[row] = bp;
}

// ---------------------------------------------------------------------------
// fp32 fallback score kernel (used only if ws is too small)
// ---------------------------------------------------------------------------
__global__ __launch_bounds__(256, 4) void score_argmin(const float* __restrict__ x,
                                                       const float* __restrict__ cb,
                                                       const float* __restrict__ c2,
                                                       const float* __restrict__ x2,
                                                       unsigned long long* __restrict__ best) {
    #pragma clang fp contract(off)
    __shared__ float As[16][128];
    __shared__ float Bs[16][128];
    const int row0 = blockIdx.x * 128;
    const int col0 = blockIdx.y * 128;
    const int t = threadIdx.x;
    const int tn = t & 15, tm = t >> 4;
    const int lrow = t >> 1, lseg = (t & 1) * 4;
    float acc[8][8];
    #pragma unroll
    for (int i = 0; i < 8; ++i)
        #pragma unroll
        for (int j = 0; j < 8; ++j) acc[i][j] = 0.f;
    const float* xp = x  + (size_t)(row0 + lrow) * DIM + lseg;
    const float* cp = cb + (size_t)(col0 + lrow) * DIM + lseg;
    for (int k0 = 0; k0 < DIM; k0 += 16) {
        float4 a0 = *(const float4*)(xp + k0);
        float4 a1 = *(const float4*)(xp + k0 + 8);
        float4 b0 = *(const float4*)(cp + k0);
        float4 b1 = *(const float4*)(cp + k0 + 8);
        __syncthreads();
        As[lseg + 0][lrow] = a0.x; As[lseg + 1][lrow] = a0.y;
        As[lseg + 2][lrow] = a0.z; As[lseg + 3][lrow] = a0.w;
        As[8 + lseg + 0][lrow] = a1.x; As[8 + lseg + 1][lrow] = a1.y;
        As[8 + lseg + 2][lrow] = a1.z; As[8 + lseg + 3][lrow] = a1.w;
        Bs[lseg + 0][lrow] = b0.x; Bs[lseg + 1][lrow] = b0.y;
        Bs[lseg + 2][lrow] = b0.z; Bs[lseg + 3][lrow] = b0.w;
        Bs[8 + lseg + 0][lrow] = b1.x; Bs[8 + lseg + 1][lrow] = b1.y;
        Bs[8 + lseg + 2][lrow] = b1.z; Bs[8 + lseg + 3][lrow] = b1.w;
        __syncthreads();
        #pragma unroll
        for (int kk = 0; kk < 16; ++kk) {
            float a[8], b[8];
            *(float4*)(a)     = *(const float4*)&As[kk][tm * 4];
            *(float4*)(a + 4) = *(const float4*)&As[kk][64 + tm * 4];
            *(float4*)(b)     = *(const float4*)&Bs[kk][tn * 4];
            *(float4*)(b + 4) = *(const float4*)&Bs[kk][64 + tn * 4];
            #pragma unroll
            for (int i = 0; i < 8; ++i)
                #pragma unroll
                for (int j = 0; j < 8; ++j)
                    acc[i][j] = fmaf(a[i], b[j], acc[i][j]);
        }
    }
    float c2v[8], x2v[8];
    #pragma unroll
    for (int j = 0; j < 4; ++j) {
        c2v[j]     = c2[col0 + tn * 4 + j];
        c2v[4 + j] = c2[col0 + 64 + tn * 4 + j];
    }
    #pragma unroll
    for (int i = 0; i < 4; ++i) {
        x2v[i]     = x2[row0 + tm * 4 + i];
        x2v[4 + i] = x2[row0 + 64 + tm * 4 + i];
    }
    #pragma unroll
    for (int i = 0; i < 8; ++i) {
        unsigned long long bp = ~0ull;
        #pragma unroll
        for (int j = 0; j < 8; ++j) {
            float tt = 2.0f * acc[i][j];
            float u  = x2v[i] - tt;
            float dd = u + c2v[j];
            int id = col0 + ((j < 4) ? (tn * 4 + j) : (64 + tn * 4 + (j - 4)));
            unsigned long long pk = ((unsigned long long)mono_f32(dd) << 32) | (unsigned int)id;
            if (pk < bp) bp = pk;
        }
        #pragma unroll
        for (int m = 1; m < 16; m <<= 1) {
            unsigned long long v = shfl_xor_u64(bp, m);
            if (v < bp) bp = v;
        }
        if (tn == 0) {
            int gr = row0 + ((i < 4) ? (tm * 4 + i) : (64 + tm * 4 + (i - 4)));
            atomicMin(&best[gr], bp);
        }
    }
}

// ---------------------------------------------------------------------------
// finalize: 16 rows per block (grid 2048, was 32768 near-empty blocks).
// Each row: 16 lanes x 16 floats (float4 x4). Gather q, write quantized,
// ids(float), per-BLOCK loss partial (shfl-group reduce, no atomics).
// ---------------------------------------------------------------------------
__global__ __launch_bounds__(256) void finalize(const float* __restrict__ x,
                                                const float* __restrict__ cb,
                                                const unsigned long long* __restrict__ best,
                                                float* __restrict__ out,
                                                float* __restrict__ partial) {
    __shared__ float rsum[16];
    const int t = threadIdx.x;
    const int rloc = t >> 4, seg = t & 15;
    const int r = blockIdx.x * 16 + rloc;
    const int id = (int)(best[r] & 0xFFFFFFFFu);
    const float4* xp = (const float4*)(x  + (size_t)r  * DIM) + seg * 4;
    const float4* cp = (const float4*)(cb + (size_t)id * DIM) + seg * 4;
    float4*       op = (float4*)(out + (size_t)r * DIM) + seg * 4;
    float s = 0.f;
    #pragma unroll
    for (int i = 0; i < 4; ++i) {
        float4 xv = xp[i], qv = cp[i];
        op[i] = qv;
        float dx = xv.x - qv.x, dy = xv.y - qv.y;
        float dz = xv.z - qv.z, dw = xv.w - qv.w;
        s += dx * dx + dy * dy + dz * dz + dw * dw;
    }
    #pragma unroll
    for (int m = 1; m < 16; m <<= 1) s += __shfl_xor(s, m, 64);
    if (seg == 0) {
        rsum[rloc] = s;
        out[(size_t)N_TOK * DIM + r] = (float)id;
    }
    __syncthreads();
    if (t == 0) {
        float bs = 0.f;
        #pragma unroll
        for (int i = 0; i < 16; ++i) bs += rsum[i];
        partial[blockIdx.x] = bs;
    }
}

// single block: sum 2048 partials, write loss scalar
__global__ __launch_bounds__(256) void reduce_loss(const float* __restrict__ partial,
                                                   float* __restrict__ out) {
    float s = 0.f;
    for (int i = threadIdx.x; i < 2048 / 4; i += 256) {
        float4 v = ((const float4*)partial)[i];
        s += (v.x + v.y) + (v.z + v.w);
    }
    #pragma unroll
    for (int o = 32; o > 0; o >>= 1) s += __shfl_down(s, o, 64);
    __shared__ float w4[4];
    if ((threadIdx.x & 63) == 0) w4[threadIdx.x >> 6] = s;
    __syncthreads();
    if (threadIdx.x == 0)
        out[(size_t)N_TOK * DIM + N_TOK] =
            (w4[0] + w4[1] + w4[2] + w4[3]) * (1.25f / ((float)N_TOK * (float)DIM));
}

// ---------------------------------------------------------------------------
extern "C" void kernel_launch(void* const* d_in, const int* in_sizes, int n_in,
                              void* d_out, int out_size, void* d_ws, size_t ws_size,
                              hipStream_t stream) {
    const float* x     = (const float*)d_in[0];
    const float* emb   = (const float*)d_in[1];
    const float* w_out = (const float*)d_in[2];
    float* out = (float*)d_out;

    char* ws = (char*)d_ws;
    unsigned long long* best = (unsigned long long*)ws;              //        0 (256 KiB)
    float* x2 = (float*)(ws + 262400);                               //   262400
    float* wT = (float*)(ws + 393472);                               //   393472 (reused as loss partial)
    float* cb = (float*)(ws + 655616);                               //   655616 (8 MiB)
    float* c2 = (float*)(ws + 9044224);                              //  9044224
    unsigned int*   gmax = (unsigned int*)(ws + 9076992);            //  9076992 (128 KiB)
    unsigned int*   ccnt = (unsigned int*)(ws + 9208064);            //  9208064 (128 KiB)
    unsigned short* cand = (unsigned short*)(ws + 9339136);          //  9339136 (4 MiB)
    unsigned short* xbf  = (unsigned short*)(ws + 13533440);         // 13533440 (16 MiB)
    unsigned short* cbbf = (unsigned short*)(ws + 30310656);         // 30310656 (4 MiB)
    float* partial = wT;                                             // 8 KiB, reuse
    const size_t NEED = 34504960;
    const bool useMfma = (ws_size >= NEED);

    transpose_w   <<<64,  256, 0, stream>>>(w_out, wT);
    build_codebook<<<KCB / KPB, 256, 0, stream>>>(emb, wT, cb);
    // fused sumsq + bf16 cast (bf16 outputs only when the MFMA path is live)
    sumsq_np_bf   <<<N_TOK * 2 / 256, 256, 0, stream>>>(x, x2,
                      useMfma ? (uint4*)xbf : (uint4*)0);
    sumsq_np_bf   <<<KCB * 2 / 256, 256, 0, stream>>>(cb, c2,
                      useMfma ? (uint4*)cbbf : (uint4*)0);

    if (useMfma) {
        hipMemsetAsync(gmax, 0, 262144, stream);   // gmax + ccnt contiguous
        score_collect <<<4096, 512, 0, stream>>>(xbf, cbbf, gmax, ccnt, cand);
        exact_select  <<<N_TOK / 4, 256, 0, stream>>>(x, cb, x2, c2, ccnt, cand, best);
    } else {
        hipMemsetAsync(best, 0xFF, 262144, stream);
        score_argmin  <<<dim3(N_TOK / 128, KCB / 128), 256, 0, stream>>>(x, cb, c2, x2, best);
    }

    finalize      <<<N_TOK / 16, 256, 0, stream>>>(x, cb, best, out, partial);
    reduce_loss   <<<1, 256, 0, stream>>>(partial, out);
}